// Round 7
// baseline (430.983 us; speedup 1.0000x reference)
//
#include <hip/hip_runtime.h>
#include <cstdint>

#define DIN 256
#define DH 128
#define DOUT 32

typedef short s16x8 __attribute__((ext_vector_type(8)));
typedef float f32x4 __attribute__((ext_vector_type(4)));

__device__ inline ushort f2bf(float f) {
    uint u = __float_as_uint(f);
    u += 0x7fff + ((u >> 16) & 1);   // round-to-nearest-even
    return (ushort)(u >> 16);
}
__device__ inline float bf_lo(uint u) { return __uint_as_float(u << 16); }
__device__ inline float bf_hi(uint u) { return __uint_as_float(u & 0xffff0000u); }
__device__ inline uint packbf(float a, float b) {
    return (uint)f2bf(a) | ((uint)f2bf(b) << 16);
}

// ---------------- degree / normalization ----------------

__global__ void k_init_deg(int* deg, int n) {
    int i = blockIdx.x * blockDim.x + threadIdx.x;
    if (i < n) deg[i] = 1;  // self-loop contributes 1
}

// XCD-partitioned count: blocks round-robin across 8 XCDs (blockIdx&7);
// range r owns dst in [r*n/8,(r+1)*n/8) -> its 50KB deg window stays in one L2.
__global__ __launch_bounds__(256) void k_count(
    const int* __restrict__ dst, int* __restrict__ deg, int e, int n) {
    int r = blockIdx.x & 7;
    int q = blockIdx.x >> 3;
    int nq = gridDim.x >> 3;
    int lo = (int)((long long)n * r >> 3);
    int hi = (int)((long long)n * (r + 1) >> 3);
    for (int i = q * blockDim.x + threadIdx.x; i < e; i += nq * blockDim.x) {
        int d = dst[i];
        if (d >= lo && d < hi) atomicAdd(&deg[d], 1);
    }
}

__global__ void k_dis(const int* __restrict__ deg, float* __restrict__ dis, int n) {
    int i = blockIdx.x * blockDim.x + threadIdx.x;
    if (i < n) dis[i] = rsqrtf((float)deg[i]);
}

// ---------------- CSR build ----------------

__global__ __launch_bounds__(256) void k_scan1(const int* __restrict__ deg,
                                               int* __restrict__ offs,
                                               int* __restrict__ bsum, int n) {
    __shared__ int sh[256];
    int base = blockIdx.x * 1024;
    int t = threadIdx.x;
    int v[4];
    int sum = 0;
    #pragma unroll
    for (int j = 0; j < 4; ++j) {
        int i = base + t * 4 + j;
        int d = (i < n) ? (deg[i] - 1) : 0;
        v[j] = sum;
        sum += d;
    }
    sh[t] = sum;
    __syncthreads();
    #pragma unroll
    for (int off = 1; off < 256; off <<= 1) {
        int x = (t >= off) ? sh[t - off] : 0;
        __syncthreads();
        if (t >= off) sh[t] += x;
        __syncthreads();
    }
    int excl = (t == 0) ? 0 : sh[t - 1];
    if (t == 255) bsum[blockIdx.x] = sh[255];
    #pragma unroll
    for (int j = 0; j < 4; ++j) {
        int i = base + t * 4 + j;
        if (i < n) offs[i] = excl + v[j];
    }
}

__global__ __launch_bounds__(256) void k_scan2(int* __restrict__ bsum, int nb) {
    __shared__ int sh[256];
    int t = threadIdx.x;
    sh[t] = (t < nb) ? bsum[t] : 0;
    __syncthreads();
    #pragma unroll
    for (int off = 1; off < 256; off <<= 1) {
        int x = (t >= off) ? sh[t - off] : 0;
        __syncthreads();
        if (t >= off) sh[t] += x;
        __syncthreads();
    }
    int excl = (t == 0) ? 0 : sh[t - 1];
    if (t < nb) bsum[t] = excl;
}

__global__ void k_scan3(int* __restrict__ offs, int* __restrict__ cursor,
                        const int* __restrict__ bsum, int n) {
    int i = blockIdx.x * blockDim.x + threadIdx.x;
    if (i < n) {
        int o = offs[i] + bsum[i >> 10];
        offs[i] = o;
        cursor[i] = o;
    }
}

// ---------------- fill: XCD-ownership partitioned by dst range ----------------

__global__ __launch_bounds__(256) void k_fill(
    const int* __restrict__ src, const int* __restrict__ dst,
    int* __restrict__ cursor, int* __restrict__ adj, int e, int n) {
    int r = blockIdx.x & 7;
    int q = blockIdx.x >> 3;
    int nq = gridDim.x >> 3;
    int lo = (int)((long long)n * r >> 3);
    int hi = (int)((long long)n * (r + 1) >> 3);
    for (int i = q * blockDim.x + threadIdx.x; i < e; i += nq * blockDim.x) {
        int d = dst[i];
        int s = src[i];
        if (d < lo || d >= hi) continue;
        int pos = atomicAdd(&cursor[d], 1);
        adj[pos] = s;
    }
}

// ---------------- GEMM1 (bf16 MFMA): hs = bf16( (x @ W1) * dis[row] ) ----------------

__global__ __launch_bounds__(256) void k_gemm1(
    const float* __restrict__ x, const float* __restrict__ W1,
    const float* __restrict__ dis, ushort* __restrict__ hs, int n) {
    __shared__ union {
        ushort w1t[128][136];   // [col][k_local]
        ushort cs[128][136];    // epilogue staging
    } u;
    __shared__ ushort xs[128][72];

    int tid = threadIdx.x;
    int row0 = blockIdx.x * 128;
    int lane = tid & 63;
    int w = tid >> 6;
    int wr0 = w * 32;
    int l15 = lane & 15;
    int koff = (lane >> 4) * 8;

    f32x4 acc[2][8];
    #pragma unroll
    for (int i = 0; i < 2; ++i)
        #pragma unroll
        for (int j = 0; j < 8; ++j)
            acc[i][j] = (f32x4){0.f, 0.f, 0.f, 0.f};

    for (int kh = 0; kh < 2; ++kh) {
        {   // stage W1^T half: w1t[c][kl] = W1[kh*128+kl][c]
            int kl = tid >> 1;
            int ch = (tid & 1) * 64;
            const float4* wr = (const float4*)(W1 + (size_t)(kh * 128 + kl) * DH + ch);
            #pragma unroll
            for (int c4 = 0; c4 < 16; ++c4) {
                float4 v = wr[c4];
                u.w1t[ch + c4 * 4 + 0][kl] = f2bf(v.x);
                u.w1t[ch + c4 * 4 + 1][kl] = f2bf(v.y);
                u.w1t[ch + c4 * 4 + 2][kl] = f2bf(v.z);
                u.w1t[ch + c4 * 4 + 3][kl] = f2bf(v.w);
            }
        }
        for (int kc2 = 0; kc2 < 2; ++kc2) {
            {   // stage x tile: 128 rows x 64 k (fp32 -> bf16)
                int r = tid >> 1;
                int half = (tid & 1) * 32;
                int rr = row0 + r; if (rr >= n) rr = n - 1;
                const float4* xr = (const float4*)(x + (size_t)rr * DIN + kh * 128 + kc2 * 64 + half);
                float4 v[8];
                #pragma unroll
                for (int q = 0; q < 8; ++q) v[q] = xr[q];
                #pragma unroll
                for (int q = 0; q < 8; ++q) {
                    ushort4 o;
                    o.x = f2bf(v[q].x); o.y = f2bf(v[q].y);
                    o.z = f2bf(v[q].z); o.w = f2bf(v[q].w);
                    *(ushort4*)&xs[r][half + q * 4] = o;
                }
            }
            __syncthreads();
            #pragma unroll
            for (int kk = 0; kk < 64; kk += 32) {
                s16x8 a0 = *(const s16x8*)&xs[wr0 + l15][kk + koff];
                s16x8 a1 = *(const s16x8*)&xs[wr0 + 16 + l15][kk + koff];
                int kl = kc2 * 64 + kk + koff;
                #pragma unroll
                for (int ct = 0; ct < 8; ++ct) {
                    s16x8 b = *(const s16x8*)&u.w1t[ct * 16 + l15][kl];
                    acc[0][ct] = __builtin_amdgcn_mfma_f32_16x16x32_bf16(a0, b, acc[0][ct], 0, 0, 0);
                    acc[1][ct] = __builtin_amdgcn_mfma_f32_16x16x32_bf16(a1, b, acc[1][ct], 0, 0, 0);
                }
            }
            __syncthreads();
        }
    }

    // epilogue: scale by dis[row], pack bf16, stage through LDS, coalesced store
    float dv[2][4];
    #pragma unroll
    for (int rt = 0; rt < 2; ++rt)
        #pragma unroll
        for (int r = 0; r < 4; ++r) {
            int rg = row0 + wr0 + rt * 16 + (lane >> 4) * 4 + r;
            if (rg >= n) rg = n - 1;
            dv[rt][r] = dis[rg];
        }
    #pragma unroll
    for (int rt = 0; rt < 2; ++rt)
        #pragma unroll
        for (int ct = 0; ct < 8; ++ct)
            #pragma unroll
            for (int r = 0; r < 4; ++r)
                u.cs[wr0 + rt * 16 + (lane >> 4) * 4 + r][ct * 16 + l15] = f2bf(acc[rt][ct][r] * dv[rt][r]);
    __syncthreads();
    {
        int r = tid >> 1;
        int half = (tid & 1) * 64;
        if (row0 + r < n) {
            uint4* dstp = (uint4*)(hs + (size_t)(row0 + r) * DH + half);
            const uint4* s = (const uint4*)&u.cs[r][half];
            #pragma unroll
            for (int q = 0; q < 8; ++q) dstp[q] = s[q];
        }
    }
}

// ---------------- agg1 + gemm2 fused ----------------
// wave per node. lane = r*16+j: group r (0..3) processes sources r,r+4,...;
// lane j covers cols [j*8, j*8+8) via one uint4 (8 bf16) per row -> 4 rows per
// load instruction, unroll 2 -> 8 rows in flight. After cross-lane reduce,
// h1 = relu(sum*dis+b1) stays in registers; gemm2 (W2 in LDS) + j-reduce
// produces h2s = (h1@W2)*dis directly. h1 never touches memory.

__global__ __launch_bounds__(256) void k_agg1g2(
    const ushort* __restrict__ hs, const float* __restrict__ dis,
    const int* __restrict__ offs, const int* __restrict__ deg,
    const int* __restrict__ adj, const float* __restrict__ b1,
    const float* __restrict__ W2, ushort* __restrict__ h2s, int n) {
    __shared__ float w2s[128][33];
    {   // stage W2 fp32: 4096 floats, coalesced
        #pragma unroll
        for (int q = 0; q < 16; ++q) {
            int f = threadIdx.x + q * 256;
            w2s[f >> 5][f & 31] = W2[f];
        }
    }
    __syncthreads();

    int node = blockIdx.x * 4 + (threadIdx.x >> 6);
    if (node >= n) return;
    int lane = threadIdx.x & 63;
    int r = lane >> 4;     // row group 0..3
    int j = lane & 15;     // col group: cols [j*8, j*8+8)

    const uint4* hu4 = (const uint4*)hs;   // row = 16 uint4
    int off = offs[node];
    int nsrc = deg[node];                  // sources: self + (deg-1) neighbors

    float a8[8] = {0.f, 0.f, 0.f, 0.f, 0.f, 0.f, 0.f, 0.f};
    int i = r;
    for (; i + 4 < nsrc; i += 8) {
        int s0 = (i == 0) ? node : adj[off + i - 1];
        int s1 = adj[off + i + 3];
        uint4 v0 = hu4[(size_t)s0 * 16 + j];
        uint4 v1 = hu4[(size_t)s1 * 16 + j];
        a8[0] += bf_lo(v0.x) + bf_lo(v1.x); a8[1] += bf_hi(v0.x) + bf_hi(v1.x);
        a8[2] += bf_lo(v0.y) + bf_lo(v1.y); a8[3] += bf_hi(v0.y) + bf_hi(v1.y);
        a8[4] += bf_lo(v0.z) + bf_lo(v1.z); a8[5] += bf_hi(v0.z) + bf_hi(v1.z);
        a8[6] += bf_lo(v0.w) + bf_lo(v1.w); a8[7] += bf_hi(v0.w) + bf_hi(v1.w);
    }
    if (i < nsrc) {
        int s0 = (i == 0) ? node : adj[off + i - 1];
        uint4 v0 = hu4[(size_t)s0 * 16 + j];
        a8[0] += bf_lo(v0.x); a8[1] += bf_hi(v0.x);
        a8[2] += bf_lo(v0.y); a8[3] += bf_hi(v0.y);
        a8[4] += bf_lo(v0.z); a8[5] += bf_hi(v0.z);
        a8[6] += bf_lo(v0.w); a8[7] += bf_hi(v0.w);
    }
    // reduce across row groups (r): lane xor 16, 32
    #pragma unroll
    for (int q = 0; q < 8; ++q) {
        a8[q] += __shfl_xor(a8[q], 16);
        a8[q] += __shfl_xor(a8[q], 32);
    }

    float dv = dis[node];
    float4 ba = ((const float4*)b1)[j * 2];
    float4 bb = ((const float4*)b1)[j * 2 + 1];
    float h1v[8];
    h1v[0] = fmaxf(a8[0] * dv + ba.x, 0.f);
    h1v[1] = fmaxf(a8[1] * dv + ba.y, 0.f);
    h1v[2] = fmaxf(a8[2] * dv + ba.z, 0.f);
    h1v[3] = fmaxf(a8[3] * dv + ba.w, 0.f);
    h1v[4] = fmaxf(a8[4] * dv + bb.x, 0.f);
    h1v[5] = fmaxf(a8[5] * dv + bb.y, 0.f);
    h1v[6] = fmaxf(a8[6] * dv + bb.z, 0.f);
    h1v[7] = fmaxf(a8[7] * dv + bb.w, 0.f);

    // gemm2 slice: lane (r,j) -> outputs [r*8,r*8+8) over k in [j*8,j*8+8)
    float p[8] = {0.f, 0.f, 0.f, 0.f, 0.f, 0.f, 0.f, 0.f};
    #pragma unroll
    for (int kk = 0; kk < 8; ++kk) {
        float hv = h1v[kk];
        const float* wrow = &w2s[j * 8 + kk][r * 8];
        #pragma unroll
        for (int oo = 0; oo < 8; ++oo) p[oo] += hv * wrow[oo];
    }
    // reduce across k groups (j): lane xor 1,2,4,8
    #pragma unroll
    for (int oo = 0; oo < 8; ++oo) {
        p[oo] += __shfl_xor(p[oo], 1);
        p[oo] += __shfl_xor(p[oo], 2);
        p[oo] += __shfl_xor(p[oo], 4);
        p[oo] += __shfl_xor(p[oo], 8);
    }
    if (j == 0) {
        uint4 ov;
        ov.x = packbf(p[0] * dv, p[1] * dv);
        ov.y = packbf(p[2] * dv, p[3] * dv);
        ov.z = packbf(p[4] * dv, p[5] * dv);
        ov.w = packbf(p[6] * dv, p[7] * dv);
        *(uint4*)(h2s + (size_t)node * DOUT + r * 8) = ov;
    }
}

// ---------------- agg2 + bias + log_softmax fused ----------------
// 32 lanes per node (2 nodes/wave). lane = rr*8+j: group rr processes sources
// rr,rr+4,...; lane j covers cols [j*4,j*4+4) via one uint2 (4 bf16) per row.

__global__ __launch_bounds__(256) void k_agg2_lsm(
    const ushort* __restrict__ h2s, const float* __restrict__ dis,
    const int* __restrict__ offs, const int* __restrict__ deg,
    const int* __restrict__ adj, const float* __restrict__ b2,
    float* __restrict__ out, int n) {
    int node = blockIdx.x * 8 + (threadIdx.x >> 5);
    if (node >= n) return;
    int t32 = threadIdx.x & 31;
    int rr = t32 >> 3;    // 0..3
    int j = t32 & 7;      // cols [j*4, j*4+4)

    const uint2* hu2 = (const uint2*)h2s;  // row = 8 uint2
    int off = offs[node];
    int nsrc = deg[node];

    float a4[4] = {0.f, 0.f, 0.f, 0.f};
    int i = rr;
    for (; i + 4 < nsrc; i += 8) {
        int s0 = (i == 0) ? node : adj[off + i - 1];
        int s1 = adj[off + i + 3];
        uint2 v0 = hu2[(size_t)s0 * 8 + j];
        uint2 v1 = hu2[(size_t)s1 * 8 + j];
        a4[0] += bf_lo(v0.x) + bf_lo(v1.x); a4[1] += bf_hi(v0.x) + bf_hi(v1.x);
        a4[2] += bf_lo(v0.y) + bf_lo(v1.y); a4[3] += bf_hi(v0.y) + bf_hi(v1.y);
    }
    if (i < nsrc) {
        int s0 = (i == 0) ? node : adj[off + i - 1];
        uint2 v0 = hu2[(size_t)s0 * 8 + j];
        a4[0] += bf_lo(v0.x); a4[1] += bf_hi(v0.x);
        a4[2] += bf_lo(v0.y); a4[3] += bf_hi(v0.y);
    }
    // reduce across rr groups: lane xor 8, 16 (stays within 32-lane node group)
    #pragma unroll
    for (int q = 0; q < 4; ++q) {
        a4[q] += __shfl_xor(a4[q], 8);
        a4[q] += __shfl_xor(a4[q], 16);
    }
    float dv = dis[node];
    float4 b = ((const float4*)b2)[j];
    float v0 = a4[0] * dv + b.x;
    float v1 = a4[1] * dv + b.y;
    float v2 = a4[2] * dv + b.z;
    float v3 = a4[3] * dv + b.w;
    float m = fmaxf(fmaxf(v0, v1), fmaxf(v2, v3));
    m = fmaxf(m, __shfl_xor(m, 1));
    m = fmaxf(m, __shfl_xor(m, 2));
    m = fmaxf(m, __shfl_xor(m, 4));
    float s = __expf(v0 - m) + __expf(v1 - m) + __expf(v2 - m) + __expf(v3 - m);
    s += __shfl_xor(s, 1);
    s += __shfl_xor(s, 2);
    s += __shfl_xor(s, 4);
    float ls = m + __logf(s);
    if (rr == 0) {
        float4 o4 = make_float4(v0 - ls, v1 - ls, v2 - ls, v3 - ls);
        *(float4*)(out + (size_t)node * DOUT + j * 4) = o4;
    }
}

extern "C" void kernel_launch(void* const* d_in, const int* in_sizes, int n_in,
                              void* d_out, int out_size, void* d_ws, size_t ws_size,
                              hipStream_t stream) {
    const float* x  = (const float*)d_in[0];
    const int*   ei = (const int*)d_in[1];
    const float* W1 = (const float*)d_in[2];
    const float* b1 = (const float*)d_in[3];
    const float* W2 = (const float*)d_in[4];
    const float* b2 = (const float*)d_in[5];
    int n = in_sizes[0] / DIN;
    int e = in_sizes[1] / 2;
    const int* src = ei;
    const int* dst = ei + e;
    float* out = (float*)d_out;

    // workspace: deg|offs|cursor|bsum|dis|adj|hs(bf16)|h2s(bf16)  ~40 MB
    char* p = (char*)d_ws;
    int*    deg    = (int*)p;     p += (size_t)n * 4;
    int*    offs   = (int*)p;     p += (size_t)n * 4;
    int*    cursor = (int*)p;     p += (size_t)n * 4;
    int*    bsum   = (int*)p;     p += 1024;
    float*  dis    = (float*)p;   p += (size_t)n * 4;
    int*    adj    = (int*)p;     p += (size_t)e * 4;
    ushort* hs     = (ushort*)p;  p += (size_t)n * DH * 2;
    ushort* h2s    = (ushort*)p;

    int nb = (n + 1023) / 1024;

    k_init_deg<<<(n + 255) / 256, 256, 0, stream>>>(deg, n);
    k_count<<<1024, 256, 0, stream>>>(dst, deg, e, n);
    k_dis<<<(n + 255) / 256, 256, 0, stream>>>(deg, dis, n);
    k_scan1<<<nb, 256, 0, stream>>>(deg, offs, bsum, n);
    k_scan2<<<1, 256, 0, stream>>>(bsum, nb);
    k_scan3<<<(n + 255) / 256, 256, 0, stream>>>(offs, cursor, bsum, n);
    k_fill<<<1024, 256, 0, stream>>>(src, dst, cursor, adj, e, n);

    k_gemm1<<<(n + 127) / 128, 256, 0, stream>>>(x, W1, dis, hs, n);
    k_agg1g2<<<(n + 3) / 4, 256, 0, stream>>>(hs, dis, offs, deg, adj, b1, W2, h2s, n);
    k_agg2_lsm<<<(n + 7) / 8, 256, 0, stream>>>(h2s, dis, offs, deg, adj, b2, out, n);
}

// Round 8
// 360.983 us; speedup vs baseline: 1.1939x; 1.1939x over previous
//
#include <hip/hip_runtime.h>
#include <cstdint>

#define DIN 256
#define DH 128
#define DOUT 32

typedef short s16x8 __attribute__((ext_vector_type(8)));
typedef float f32x4 __attribute__((ext_vector_type(4)));

__device__ inline ushort f2bf(float f) {
    uint u = __float_as_uint(f);
    u += 0x7fff + ((u >> 16) & 1);   // round-to-nearest-even
    return (ushort)(u >> 16);
}
__device__ inline float bf_lo(uint u) { return __uint_as_float(u << 16); }
__device__ inline float bf_hi(uint u) { return __uint_as_float(u & 0xffff0000u); }
__device__ inline uint packbf(float a, float b) {
    return (uint)f2bf(a) | ((uint)f2bf(b) << 16);
}

// ---------------- degree / normalization ----------------

__global__ void k_init_deg(int* deg, int n) {
    int i = blockIdx.x * blockDim.x + threadIdx.x;
    if (i < n) deg[i] = 1;  // self-loop contributes 1
}

// XCD-partitioned count: blocks round-robin across 8 XCDs (blockIdx&7);
// range r owns dst in [r*n/8,(r+1)*n/8) -> its 50KB deg window stays in one L2.
__global__ __launch_bounds__(256) void k_count(
    const int* __restrict__ dst, int* __restrict__ deg, int e, int n) {
    int r = blockIdx.x & 7;
    int q = blockIdx.x >> 3;
    int nq = gridDim.x >> 3;
    int lo = (int)((long long)n * r >> 3);
    int hi = (int)((long long)n * (r + 1) >> 3);
    for (int i = q * blockDim.x + threadIdx.x; i < e; i += nq * blockDim.x) {
        int d = dst[i];
        if (d >= lo && d < hi) atomicAdd(&deg[d], 1);
    }
}

// ---------------- CSR build ----------------

__global__ __launch_bounds__(256) void k_scan1(const int* __restrict__ deg,
                                               int* __restrict__ offs,
                                               int* __restrict__ bsum, int n) {
    __shared__ int sh[256];
    int base = blockIdx.x * 1024;
    int t = threadIdx.x;
    int v[4];
    int sum = 0;
    #pragma unroll
    for (int j = 0; j < 4; ++j) {
        int i = base + t * 4 + j;
        int d = (i < n) ? (deg[i] - 1) : 0;
        v[j] = sum;
        sum += d;
    }
    sh[t] = sum;
    __syncthreads();
    #pragma unroll
    for (int off = 1; off < 256; off <<= 1) {
        int x = (t >= off) ? sh[t - off] : 0;
        __syncthreads();
        if (t >= off) sh[t] += x;
        __syncthreads();
    }
    int excl = (t == 0) ? 0 : sh[t - 1];
    if (t == 255) bsum[blockIdx.x] = sh[255];
    #pragma unroll
    for (int j = 0; j < 4; ++j) {
        int i = base + t * 4 + j;
        if (i < n) offs[i] = excl + v[j];
    }
}

__global__ __launch_bounds__(256) void k_scan2(int* __restrict__ bsum, int nb) {
    __shared__ int sh[256];
    int t = threadIdx.x;
    sh[t] = (t < nb) ? bsum[t] : 0;
    __syncthreads();
    #pragma unroll
    for (int off = 1; off < 256; off <<= 1) {
        int x = (t >= off) ? sh[t - off] : 0;
        __syncthreads();
        if (t >= off) sh[t] += x;
        __syncthreads();
    }
    int excl = (t == 0) ? 0 : sh[t - 1];
    if (t < nb) bsum[t] = excl;
}

// scan3 + dis fused (one less launch)
__global__ void k_scan3(int* __restrict__ offs, int* __restrict__ cursor,
                        const int* __restrict__ bsum, const int* __restrict__ deg,
                        float* __restrict__ dis, int n) {
    int i = blockIdx.x * blockDim.x + threadIdx.x;
    if (i < n) {
        int o = offs[i] + bsum[i >> 10];
        offs[i] = o;
        cursor[i] = o;
        dis[i] = rsqrtf((float)deg[i]);
    }
}

// ---------------- fill: XCD-ownership partitioned by dst range ----------------

__global__ __launch_bounds__(256) void k_fill(
    const int* __restrict__ src, const int* __restrict__ dst,
    int* __restrict__ cursor, int* __restrict__ adj, int e, int n) {
    int r = blockIdx.x & 7;
    int q = blockIdx.x >> 3;
    int nq = gridDim.x >> 3;
    int lo = (int)((long long)n * r >> 3);
    int hi = (int)((long long)n * (r + 1) >> 3);
    for (int i = q * blockDim.x + threadIdx.x; i < e; i += nq * blockDim.x) {
        int d = dst[i];
        int s = src[i];
        if (d < lo || d >= hi) continue;
        int pos = atomicAdd(&cursor[d], 1);
        adj[pos] = s;
    }
}

// ---------------- GEMM1 (bf16 MFMA): hs = bf16( (x @ W1) * dis[row] ) ----------------

__global__ __launch_bounds__(256) void k_gemm1(
    const float* __restrict__ x, const float* __restrict__ W1,
    const float* __restrict__ dis, ushort* __restrict__ hs, int n) {
    __shared__ union {
        ushort w1t[128][136];   // [col][k_local]
        ushort cs[128][136];    // epilogue staging
    } u;
    __shared__ ushort xs[128][72];

    int tid = threadIdx.x;
    int row0 = blockIdx.x * 128;
    int lane = tid & 63;
    int w = tid >> 6;
    int wr0 = w * 32;
    int l15 = lane & 15;
    int koff = (lane >> 4) * 8;

    f32x4 acc[2][8];
    #pragma unroll
    for (int i = 0; i < 2; ++i)
        #pragma unroll
        for (int j = 0; j < 8; ++j)
            acc[i][j] = (f32x4){0.f, 0.f, 0.f, 0.f};

    for (int kh = 0; kh < 2; ++kh) {
        {   // stage W1^T half: w1t[c][kl] = W1[kh*128+kl][c]
            int kl = tid >> 1;
            int ch = (tid & 1) * 64;
            const float4* wr = (const float4*)(W1 + (size_t)(kh * 128 + kl) * DH + ch);
            #pragma unroll
            for (int c4 = 0; c4 < 16; ++c4) {
                float4 v = wr[c4];
                u.w1t[ch + c4 * 4 + 0][kl] = f2bf(v.x);
                u.w1t[ch + c4 * 4 + 1][kl] = f2bf(v.y);
                u.w1t[ch + c4 * 4 + 2][kl] = f2bf(v.z);
                u.w1t[ch + c4 * 4 + 3][kl] = f2bf(v.w);
            }
        }
        for (int kc2 = 0; kc2 < 2; ++kc2) {
            {   // stage x tile: 128 rows x 64 k (fp32 -> bf16)
                int r = tid >> 1;
                int half = (tid & 1) * 32;
                int rr = row0 + r; if (rr >= n) rr = n - 1;
                const float4* xr = (const float4*)(x + (size_t)rr * DIN + kh * 128 + kc2 * 64 + half);
                float4 v[8];
                #pragma unroll
                for (int q = 0; q < 8; ++q) v[q] = xr[q];
                #pragma unroll
                for (int q = 0; q < 8; ++q) {
                    ushort4 o;
                    o.x = f2bf(v[q].x); o.y = f2bf(v[q].y);
                    o.z = f2bf(v[q].z); o.w = f2bf(v[q].w);
                    *(ushort4*)&xs[r][half + q * 4] = o;
                }
            }
            __syncthreads();
            #pragma unroll
            for (int kk = 0; kk < 64; kk += 32) {
                s16x8 a0 = *(const s16x8*)&xs[wr0 + l15][kk + koff];
                s16x8 a1 = *(const s16x8*)&xs[wr0 + 16 + l15][kk + koff];
                int kl = kc2 * 64 + kk + koff;
                #pragma unroll
                for (int ct = 0; ct < 8; ++ct) {
                    s16x8 b = *(const s16x8*)&u.w1t[ct * 16 + l15][kl];
                    acc[0][ct] = __builtin_amdgcn_mfma_f32_16x16x32_bf16(a0, b, acc[0][ct], 0, 0, 0);
                    acc[1][ct] = __builtin_amdgcn_mfma_f32_16x16x32_bf16(a1, b, acc[1][ct], 0, 0, 0);
                }
            }
            __syncthreads();
        }
    }

    // epilogue: scale by dis[row], pack bf16, stage through LDS, coalesced store
    float dv[2][4];
    #pragma unroll
    for (int rt = 0; rt < 2; ++rt)
        #pragma unroll
        for (int r = 0; r < 4; ++r) {
            int rg = row0 + wr0 + rt * 16 + (lane >> 4) * 4 + r;
            if (rg >= n) rg = n - 1;
            dv[rt][r] = dis[rg];
        }
    #pragma unroll
    for (int rt = 0; rt < 2; ++rt)
        #pragma unroll
        for (int ct = 0; ct < 8; ++ct)
            #pragma unroll
            for (int r = 0; r < 4; ++r)
                u.cs[wr0 + rt * 16 + (lane >> 4) * 4 + r][ct * 16 + l15] = f2bf(acc[rt][ct][r] * dv[rt][r]);
    __syncthreads();
    {
        int r = tid >> 1;
        int half = (tid & 1) * 64;
        if (row0 + r < n) {
            uint4* dstp = (uint4*)(hs + (size_t)(row0 + r) * DH + half);
            const uint4* s = (const uint4*)&u.cs[r][half];
            #pragma unroll
            for (int q = 0; q < 8; ++q) dstp[q] = s[q];
        }
    }
}

// ---------------- agg1: h1 = bf16(relu( dis[d]*(hs[d]+sum_nb hs[s]) + b1 )) ----------
// wave per node. lane = r*16+j: group r (0..3) processes sources r, r+4, ...;
// lane j covers cols [j*8, j*8+8) via one uint4 (8 bf16) -> one load instruction
// fetches 4 full rows; unroll 2 -> 8 rows in flight. Cross-r reduce: 2 shfl_xor.

__global__ __launch_bounds__(256) void k_agg1(
    const ushort* __restrict__ hs, const float* __restrict__ dis,
    const int* __restrict__ offs, const int* __restrict__ deg,
    const int* __restrict__ adj, const float* __restrict__ b1,
    ushort* __restrict__ h1, int n) {
    int node = blockIdx.x * 4 + (threadIdx.x >> 6);
    if (node >= n) return;
    int lane = threadIdx.x & 63;
    int r = lane >> 4;     // row group 0..3
    int j = lane & 15;     // col group: cols [j*8, j*8+8)

    const uint4* hu4 = (const uint4*)hs;   // row = 16 uint4
    int off = offs[node];
    int nsrc = deg[node];                  // self + (deg-1) neighbors

    float a8[8] = {0.f, 0.f, 0.f, 0.f, 0.f, 0.f, 0.f, 0.f};
    int i = r;
    for (; i + 4 < nsrc; i += 8) {
        int s0 = (i == 0) ? node : adj[off + i - 1];
        int s1 = adj[off + i + 3];
        uint4 v0 = hu4[(size_t)s0 * 16 + j];
        uint4 v1 = hu4[(size_t)s1 * 16 + j];
        a8[0] += bf_lo(v0.x) + bf_lo(v1.x); a8[1] += bf_hi(v0.x) + bf_hi(v1.x);
        a8[2] += bf_lo(v0.y) + bf_lo(v1.y); a8[3] += bf_hi(v0.y) + bf_hi(v1.y);
        a8[4] += bf_lo(v0.z) + bf_lo(v1.z); a8[5] += bf_hi(v0.z) + bf_hi(v1.z);
        a8[6] += bf_lo(v0.w) + bf_lo(v1.w); a8[7] += bf_hi(v0.w) + bf_hi(v1.w);
    }
    if (i < nsrc) {
        int s0 = (i == 0) ? node : adj[off + i - 1];
        uint4 v0 = hu4[(size_t)s0 * 16 + j];
        a8[0] += bf_lo(v0.x); a8[1] += bf_hi(v0.x);
        a8[2] += bf_lo(v0.y); a8[3] += bf_hi(v0.y);
        a8[4] += bf_lo(v0.z); a8[5] += bf_hi(v0.z);
        a8[6] += bf_lo(v0.w); a8[7] += bf_hi(v0.w);
    }
    #pragma unroll
    for (int q = 0; q < 8; ++q) {
        a8[q] += __shfl_xor(a8[q], 16);
        a8[q] += __shfl_xor(a8[q], 32);
    }

    float dv = dis[node];
    float4 ba = ((const float4*)b1)[j * 2];
    float4 bb = ((const float4*)b1)[j * 2 + 1];
    if (r == 0) {
        uint4 ov;
        ov.x = packbf(fmaxf(a8[0] * dv + ba.x, 0.f), fmaxf(a8[1] * dv + ba.y, 0.f));
        ov.y = packbf(fmaxf(a8[2] * dv + ba.z, 0.f), fmaxf(a8[3] * dv + ba.w, 0.f));
        ov.z = packbf(fmaxf(a8[4] * dv + bb.x, 0.f), fmaxf(a8[5] * dv + bb.y, 0.f));
        ov.w = packbf(fmaxf(a8[6] * dv + bb.z, 0.f), fmaxf(a8[7] * dv + bb.w, 0.f));
        ((uint4*)h1)[(size_t)node * 16 + j] = ov;
    }
}

// ---------------- GEMM2: h2s = bf16( (h1 @ W2) * dis[row] ) ----------------

__global__ __launch_bounds__(256) void k_gemm2(
    const ushort* __restrict__ h1, const float* __restrict__ W2,
    const float* __restrict__ dis, ushort* __restrict__ h2s, int n) {
    int t = blockIdx.x * blockDim.x + threadIdx.x;
    int row = t >> 3;
    int cg = t & 7;
    if (row >= n) return;
    const uint2* hr = (const uint2*)(h1 + (size_t)row * DH);
    const float4* w4 = (const float4*)W2;
    float4 acc = make_float4(0.f, 0.f, 0.f, 0.f);
    #pragma unroll 8
    for (int k4 = 0; k4 < DH / 4; ++k4) {
        uint2 au = hr[k4];
        float a0 = bf_lo(au.x), a1 = bf_hi(au.x), a2 = bf_lo(au.y), a3 = bf_hi(au.y);
        float4 w0 = w4[(k4 * 4 + 0) * 8 + cg];
        float4 w1 = w4[(k4 * 4 + 1) * 8 + cg];
        float4 w2 = w4[(k4 * 4 + 2) * 8 + cg];
        float4 w3 = w4[(k4 * 4 + 3) * 8 + cg];
        acc.x += a0 * w0.x + a1 * w1.x + a2 * w2.x + a3 * w3.x;
        acc.y += a0 * w0.y + a1 * w1.y + a2 * w2.y + a3 * w3.y;
        acc.z += a0 * w0.z + a1 * w1.z + a2 * w2.z + a3 * w3.z;
        acc.w += a0 * w0.w + a1 * w1.w + a2 * w2.w + a3 * w3.w;
    }
    float dv = dis[row];
    ushort4 o;
    o.x = f2bf(acc.x * dv); o.y = f2bf(acc.y * dv);
    o.z = f2bf(acc.z * dv); o.w = f2bf(acc.w * dv);
    *(ushort4*)(h2s + (size_t)row * DOUT + cg * 4) = o;
}

// ---------------- agg2 + bias + log_softmax fused ----------------
// 32 lanes per node. lane = rr*8+j: group rr processes sources rr, rr+4, ...;
// lane j covers cols [j*4, j*4+4) via one uint2 (4 bf16) -> 4 rows per instr.

__global__ __launch_bounds__(256) void k_agg2_lsm(
    const ushort* __restrict__ h2s, const float* __restrict__ dis,
    const int* __restrict__ offs, const int* __restrict__ deg,
    const int* __restrict__ adj, const float* __restrict__ b2,
    float* __restrict__ out, int n) {
    int node = blockIdx.x * 8 + (threadIdx.x >> 5);
    if (node >= n) return;
    int t32 = threadIdx.x & 31;
    int rr = t32 >> 3;    // 0..3
    int j = t32 & 7;      // cols [j*4, j*4+4)

    const uint2* hu2 = (const uint2*)h2s;  // row = 8 uint2
    int off = offs[node];
    int nsrc = deg[node];

    float a4[4] = {0.f, 0.f, 0.f, 0.f};
    int i = rr;
    for (; i + 4 < nsrc; i += 8) {
        int s0 = (i == 0) ? node : adj[off + i - 1];
        int s1 = adj[off + i + 3];
        uint2 v0 = hu2[(size_t)s0 * 8 + j];
        uint2 v1 = hu2[(size_t)s1 * 8 + j];
        a4[0] += bf_lo(v0.x) + bf_lo(v1.x); a4[1] += bf_hi(v0.x) + bf_hi(v1.x);
        a4[2] += bf_lo(v0.y) + bf_lo(v1.y); a4[3] += bf_hi(v0.y) + bf_hi(v1.y);
    }
    if (i < nsrc) {
        int s0 = (i == 0) ? node : adj[off + i - 1];
        uint2 v0 = hu2[(size_t)s0 * 8 + j];
        a4[0] += bf_lo(v0.x); a4[1] += bf_hi(v0.x);
        a4[2] += bf_lo(v0.y); a4[3] += bf_hi(v0.y);
    }
    #pragma unroll
    for (int q = 0; q < 4; ++q) {
        a4[q] += __shfl_xor(a4[q], 8);
        a4[q] += __shfl_xor(a4[q], 16);
    }
    float dv = dis[node];
    float4 b = ((const float4*)b2)[j];
    float v0 = a4[0] * dv + b.x;
    float v1 = a4[1] * dv + b.y;
    float v2 = a4[2] * dv + b.z;
    float v3 = a4[3] * dv + b.w;
    float m = fmaxf(fmaxf(v0, v1), fmaxf(v2, v3));
    m = fmaxf(m, __shfl_xor(m, 1));
    m = fmaxf(m, __shfl_xor(m, 2));
    m = fmaxf(m, __shfl_xor(m, 4));
    float s = __expf(v0 - m) + __expf(v1 - m) + __expf(v2 - m) + __expf(v3 - m);
    s += __shfl_xor(s, 1);
    s += __shfl_xor(s, 2);
    s += __shfl_xor(s, 4);
    float ls = m + __logf(s);
    if (rr == 0) {
        float4 o4 = make_float4(v0 - ls, v1 - ls, v2 - ls, v3 - ls);
        *(float4*)(out + (size_t)node * DOUT + j * 4) = o4;
    }
}

extern "C" void kernel_launch(void* const* d_in, const int* in_sizes, int n_in,
                              void* d_out, int out_size, void* d_ws, size_t ws_size,
                              hipStream_t stream) {
    const float* x  = (const float*)d_in[0];
    const int*   ei = (const int*)d_in[1];
    const float* W1 = (const float*)d_in[2];
    const float* b1 = (const float*)d_in[3];
    const float* W2 = (const float*)d_in[4];
    const float* b2 = (const float*)d_in[5];
    int n = in_sizes[0] / DIN;
    int e = in_sizes[1] / 2;
    const int* src = ei;
    const int* dst = ei + e;
    float* out = (float*)d_out;

    // workspace: deg|offs|cursor|bsum|dis|adj|hs(bf16)|h1(bf16)|h2s(bf16)  ~66 MB
    char* p = (char*)d_ws;
    int*    deg    = (int*)p;     p += (size_t)n * 4;
    int*    offs   = (int*)p;     p += (size_t)n * 4;
    int*    cursor = (int*)p;     p += (size_t)n * 4;
    int*    bsum   = (int*)p;     p += 1024;
    float*  dis    = (float*)p;   p += (size_t)n * 4;
    int*    adj    = (int*)p;     p += (size_t)e * 4;
    ushort* hs     = (ushort*)p;  p += (size_t)n * DH * 2;
    ushort* h1     = (ushort*)p;  p += (size_t)n * DH * 2;
    ushort* h2s    = (ushort*)p;

    int nb = (n + 1023) / 1024;

    k_init_deg<<<(n + 255) / 256, 256, 0, stream>>>(deg, n);
    k_count<<<1024, 256, 0, stream>>>(dst, deg, e, n);
    k_scan1<<<nb, 256, 0, stream>>>(deg, offs, bsum, n);
    k_scan2<<<1, 256, 0, stream>>>(bsum, nb);
    k_scan3<<<(n + 255) / 256, 256, 0, stream>>>(offs, cursor, bsum, deg, dis, n);
    k_fill<<<1024, 256, 0, stream>>>(src, dst, cursor, adj, e, n);

    k_gemm1<<<(n + 127) / 128, 256, 0, stream>>>(x, W1, dis, hs, n);
    k_agg1<<<(n + 3) / 4, 256, 0, stream>>>(hs, dis, offs, deg, adj, b1, h1, n);
    k_gemm2<<<(n * 8 + 255) / 256, 256, 0, stream>>>(h1, W2, dis, h2s, n);
    k_agg2_lsm<<<(n + 7) / 8, 256, 0, stream>>>(h2s, dis, offs, deg, adj, b2, out, n);
}